// Round 8
// baseline (171.863 us; speedup 1.0000x reference)
//
#include <hip/hip_runtime.h>
#include <hip/hip_bf16.h>

// Problem constants
#define B_  4
#define S_  2048
#define D_  256
#define H_  8
#define HD_ 32
#define K_  204          // int(2048 * 0.1)
#define SCALE_ 0.17677669529663687f  // 1/sqrt(32)

// ---- workspace layout (float offsets; all %4==0 -> 16B aligned) ----
#define OFF_IMP    0          // 8192 floats
#define OFF_META   8192       // 16 ints
#define OFF_KIDX   8208       // 1024 ints
#define OFF_KG     9232       // 208896 shorts [B][K_][256] bf16 (col = h*32+d)
#define OFF_VT     113680     // 229376 shorts [B][256][224] bf16 (V^T, cols 204.. zeroed)
#define OFF_Q      228368     // 2097152 shorts [B*S, D] bf16
#define OFF_XH     1276944    // 2097152 shorts: x hi plane
#define OFF_XL     2325520    // 2097152 shorts: x lo plane
#define OFF_WIH    3374096    // 196608 shorts: w_in (768x256) hi
#define OFF_WIL    3472400    // 196608 shorts: w_in lo
#define OFF_WOH    3570704    // 65536 shorts: w_out hi
#define OFF_WOL    3603472    // 65536 shorts: w_out lo
// total ~14.6 MB

#define GSTR 80    // gemm LDS row stride (shorts)
#define PSTR 228   // attn P row stride (shorts)
#define VSTR 232   // attn V^T LDS row stride (shorts; 464B rows, 16B-aligned)
#define AOSTR 264  // attn-out LDS row stride (shorts; 528B = 33 word-quads -> 2-way only)

typedef __attribute__((ext_vector_type(8))) short short8v;
typedef __attribute__((ext_vector_type(4))) float f32x4;

static __device__ __forceinline__ unsigned short f2bf(float f) {
    unsigned int u = __float_as_uint(f);
    u += 0x7FFFu + ((u >> 16) & 1u);      // round-to-nearest-even
    return (unsigned short)(u >> 16);
}
static __device__ __forceinline__ float bf2f(unsigned short h) {
    return __uint_as_float((unsigned int)h << 16);
}
static __device__ __forceinline__ short8v ld_bf8(const unsigned short* p) {
    union { unsigned int u[4]; short8v v; } cv;
    const uint2 a  = *(const uint2*)(p);
    const uint2 b2 = *(const uint2*)(p + 4);
    cv.u[0] = a.x; cv.u[1] = a.y; cv.u[2] = b2.x; cv.u[3] = b2.y;
    return cv.v;
}
// split 8 contiguous fp32 -> bf16 hi/lo planes (16B store each)
static __device__ __forceinline__ void split_store8(
    const float* __restrict__ src, unsigned short* dh, unsigned short* dl)
{
    short8v h, l;
    #pragma unroll
    for (int e = 0; e < 8; ++e) {
        const float f = src[e];
        const unsigned short hh = f2bf(f);
        h[e] = (short)hh;
        l[e] = (short)f2bf(f - bf2f(hh));
    }
    *(short8v*)dh = h;
    *(short8v*)dl = l;
}

// ---------------- kernel 1: gate MLP + x/weight plane conversion ----------------
__global__ __launch_bounds__(256) void gate_kernel(
    const float* __restrict__ x, const float* __restrict__ gw1,
    const float* __restrict__ gb1, const float* __restrict__ gw2,
    const float* __restrict__ w_in, const float* __restrict__ w_out, float* ws)
{
    const int t0 = blockIdx.x * 8;
    const int tid = threadIdx.x;
    __shared__ __align__(16) float xs[8 * D_];
    __shared__ float hred[8 * 64];

    const float4* src = (const float4*)(x + (size_t)t0 * D_);
    ((float4*)xs)[tid]       = src[tid];
    ((float4*)xs)[tid + 256] = src[tid + 256];
    __syncthreads();

    // emit x bf16 hi/lo planes from the staged tile (no extra global reads)
    {
        unsigned short* XH = (unsigned short*)(ws + OFF_XH);
        unsigned short* XL = (unsigned short*)(ws + OFF_XL);
        split_store8(xs + tid * 8, XH + (size_t)t0 * D_ + tid * 8,
                                   XL + (size_t)t0 * D_ + tid * 8);
    }
    // blocks 0..127: convert w_in (768x256) and w_out (256x256) to planes
    if (blockIdx.x < 128) {
        const int e0 = blockIdx.x * 2048 + tid * 8;
        if (e0 < 196608) {
            split_store8(w_in + e0, (unsigned short*)(ws + OFF_WIH) + e0,
                                    (unsigned short*)(ws + OFF_WIL) + e0);
        } else {
            const int e = e0 - 196608;
            split_store8(w_out + e, (unsigned short*)(ws + OFF_WOH) + e,
                                    (unsigned short*)(ws + OFF_WOL) + e);
        }
    }
    if (blockIdx.x == 0 && tid < 16) ((int*)(ws + OFF_META))[tid] = 0;

    const int c = tid & 3, f = tid >> 2;
    float4 wv[16];
    const float4* wr = (const float4*)(gw1 + (size_t)f * D_) + c;
    #pragma unroll
    for (int j = 0; j < 16; ++j) wv[j] = wr[j * 4];
    const float bb = gb1[f], g2 = gw2[f];

    #pragma unroll
    for (int tk = 0; tk < 8; ++tk) {
        const float4* xr = (const float4*)(xs + tk * D_) + c;
        float a = 0.0f;
        #pragma unroll
        for (int j = 0; j < 16; ++j) {
            float4 xv = xr[j * 4];
            a += wv[j].x*xv.x + wv[j].y*xv.y + wv[j].z*xv.z + wv[j].w*xv.w;
        }
        a += __shfl_xor(a, 1);
        a += __shfl_xor(a, 2);
        if (c == 0) hred[tk * 64 + f] = fmaxf(a + bb, 0.0f) * g2;
    }
    __syncthreads();

    const int tk = tid >> 5, ln = tid & 31;
    float s = hred[tk * 64 + ln] + hred[tk * 64 + ln + 32];
    #pragma unroll
    for (int o = 16; o; o >>= 1) s += __shfl_xor(s, o, 32);
    if (ln == 0) ws[OFF_IMP + t0 + tk] = s;
}

// ---------------- kernel 2: exact rank -> ticketed compact index (unsorted) ----------------
// kept set identical to lax.top_k (rank = #greater + #equal-with-smaller-index < K).
// Slot order nondeterministic; attention is key-order invariant (validated r4..r7).
__global__ __launch_bounds__(256) void rank_kernel(
    const float* __restrict__ ws_imp, int* kidx, int* meta)
{
    const int b  = blockIdx.x >> 7;
    const int ic = blockIdx.x & 127;
    const int tid = threadIdx.x;
    __shared__ __align__(16) float vs[S_];
    const float* src = ws_imp + b * S_;
    #pragma unroll
    for (int cc = 0; cc < 2; ++cc)
        ((float4*)vs)[tid + cc*256] = ((const float4*)src)[tid + cc*256];
    __syncthreads();

    const int il = tid >> 4;
    const int c  = tid & 15;
    const int i  = ic * 16 + il;
    const float vi = vs[i];
    int gt = 0, eq = 0;
    const float4* v4 = (const float4*)vs + c * 32;
    #pragma unroll 8
    for (int t = 0; t < 32; ++t) {
        const int j4 = (t + c) & 31;
        float4 w = v4[j4];
        const int base = c * 128 + j4 * 4;
        gt += (w.x > vi); eq += (w.x == vi) && (base + 0 < i);
        gt += (w.y > vi); eq += (w.y == vi) && (base + 1 < i);
        gt += (w.z > vi); eq += (w.z == vi) && (base + 2 < i);
        gt += (w.w > vi); eq += (w.w == vi) && (base + 3 < i);
    }
    int r = gt + eq;
    r += __shfl_xor(r, 1);
    r += __shfl_xor(r, 2);
    r += __shfl_xor(r, 4);
    r += __shfl_xor(r, 8);
    if (c == 0 && r < K_) {
        const int p = atomicAdd(&meta[2 + b], 1);
        kidx[b * K_ + p] = i;
    }
}

// ---------------- kernel 3: fused projection (Q GEMM + gathered KV GEMM) ----------------
// blockIdx.x < 128: Q tile; else KV tile for batch y (w_in rows 256..768).
// Split-bf16: C ~= Ah*Wh + Ah*Wl + Al*Wh, fp32 accum.
// K out: KG[b][j][256]; V out: transposed VT[b][d][224] with cols 204..223 zeroed.
__global__ __launch_bounds__(256) void proj_kernel(
    const unsigned short* __restrict__ XH, const unsigned short* __restrict__ XL,
    const unsigned short* __restrict__ WIH, const unsigned short* __restrict__ WIL,
    const float* __restrict__ b_in, unsigned short* __restrict__ Qb,
    unsigned short* __restrict__ KG, unsigned short* __restrict__ VTg,
    const int* __restrict__ kidx)
{
    __shared__ __align__(16) unsigned short Ash[64 * GSTR];
    __shared__ __align__(16) unsigned short Asl[64 * GSTR];
    __shared__ __align__(16) unsigned short Bsh[64 * GSTR];
    __shared__ __align__(16) unsigned short Bsl[64 * GSTR];

    const int tid = threadIdx.x;
    const bool isQ = (blockIdx.x < 128);
    const int lane = tid & 63, w = tid >> 6;
    const int c = lane & 15, g = lane >> 4;
    const int mq = w >> 1, nq = w & 1;
    const int srow = tid >> 2, sseg = tid & 3;

    int m0, n0, b = blockIdx.y;
    size_t arow;   // A-plane row index
    int brow;      // w_in row index
    if (isQ) {
        m0 = blockIdx.x * 64; n0 = blockIdx.y * 64;
        arow = (size_t)(m0 + srow);
        brow = n0 + srow;
    } else {
        const int kx = blockIdx.x - 128;
        m0 = (kx & 3) * 64; n0 = (kx >> 2) * 64;
        const int tok = kidx[b * K_ + min(m0 + srow, K_ - 1)];
        arow = (size_t)b * S_ + tok;
        brow = D_ + n0 + srow;
    }
    const unsigned short* Aph = XH + arow * D_ + sseg * 16;
    const unsigned short* Apl = XL + arow * D_ + sseg * 16;
    const unsigned short* Bph = WIH + (size_t)brow * D_ + sseg * 16;
    const unsigned short* Bpl = WIL + (size_t)brow * D_ + sseg * 16;

    const f32x4 zf = {0.0f, 0.0f, 0.0f, 0.0f};
    f32x4 acc[2][2] = {{zf, zf}, {zf, zf}};

    short8v arh[2], arl[2], brh[2], brl[2];
    #pragma unroll
    for (int u = 0; u < 2; ++u) {
        arh[u] = *(const short8v*)(Aph + u*8); arl[u] = *(const short8v*)(Apl + u*8);
        brh[u] = *(const short8v*)(Bph + u*8); brl[u] = *(const short8v*)(Bpl + u*8);
    }

    for (int k0 = 0; k0 < D_; k0 += 64) {
        __syncthreads();
        #pragma unroll
        for (int u = 0; u < 2; ++u) {
            *(short8v*)&Ash[srow*GSTR + sseg*16 + u*8] = arh[u];
            *(short8v*)&Asl[srow*GSTR + sseg*16 + u*8] = arl[u];
            *(short8v*)&Bsh[srow*GSTR + sseg*16 + u*8] = brh[u];
            *(short8v*)&Bsl[srow*GSTR + sseg*16 + u*8] = brl[u];
        }
        __syncthreads();
        if (k0 + 64 < D_) {
            #pragma unroll
            for (int u = 0; u < 2; ++u) {
                arh[u] = *(const short8v*)(Aph + k0 + 64 + u*8);
                arl[u] = *(const short8v*)(Apl + k0 + 64 + u*8);
                brh[u] = *(const short8v*)(Bph + k0 + 64 + u*8);
                brl[u] = *(const short8v*)(Bpl + k0 + 64 + u*8);
            }
        }
        #pragma unroll
        for (int ks = 0; ks < 2; ++ks) {
            short8v am[2][2], bm[2][2];
            #pragma unroll
            for (int t = 0; t < 2; ++t) {
                const int ra = (mq*32 + t*16 + c) * GSTR + ks*32 + g*8;
                am[t][0] = *(const short8v*)&Ash[ra];
                am[t][1] = *(const short8v*)&Asl[ra];
                const int rb = (nq*32 + t*16 + c) * GSTR + ks*32 + g*8;
                bm[t][0] = *(const short8v*)&Bsh[rb];
                bm[t][1] = *(const short8v*)&Bsl[rb];
            }
            #pragma unroll
            for (int mt = 0; mt < 2; ++mt)
                #pragma unroll
                for (int nt = 0; nt < 2; ++nt) {
                    acc[mt][nt] = __builtin_amdgcn_mfma_f32_16x16x32_bf16(am[mt][0], bm[nt][0], acc[mt][nt], 0, 0, 0);
                    acc[mt][nt] = __builtin_amdgcn_mfma_f32_16x16x32_bf16(am[mt][0], bm[nt][1], acc[mt][nt], 0, 0, 0);
                    acc[mt][nt] = __builtin_amdgcn_mfma_f32_16x16x32_bf16(am[mt][1], bm[nt][0], acc[mt][nt], 0, 0, 0);
                }
        }
    }

    if (isQ) {
        #pragma unroll
        for (int nt = 0; nt < 2; ++nt) {
            const int n = n0 + nq*32 + nt*16 + c;
            const float bv = b_in[n];
            #pragma unroll
            for (int mt = 0; mt < 2; ++mt) {
                const int m = m0 + mq*32 + mt*16 + g*4;
                #pragma unroll
                for (int r = 0; r < 4; ++r)
                    Qb[(size_t)(m + r) * D_ + n] = f2bf(acc[mt][nt][r] + bv);
            }
        }
    } else {
        #pragma unroll
        for (int nt = 0; nt < 2; ++nt) {
            const int n = n0 + nq*32 + nt*16 + c;           // 0..511
            const float bv = b_in[D_ + n];
            #pragma unroll
            for (int mt = 0; mt < 2; ++mt) {
                const int j = m0 + mq*32 + mt*16 + g*4;     // key slot
                #pragma unroll
                for (int r = 0; r < 4; ++r) {
                    const int jj = j + r;
                    if (n < 256) {
                        if (jj < K_)
                            KG[((size_t)b * K_ + jj) * 256 + n] = f2bf(acc[mt][nt][r] + bv);
                    } else {
                        if (jj < 224)
                            VTg[((size_t)b * 256 + (n - 256)) * 224 + jj] =
                                (jj < K_) ? f2bf(acc[mt][nt][r] + bv) : (unsigned short)0;
                    }
                }
            }
        }
    }
}

// ---------------- kernel 4: fused attention + out-projection ----------------
// One block per (32-query tile, batch). Phase 1: loop over 8 heads with the
// verified attn-tile math; PV writes hi/lo bf16 AO into LDS (no HBM round-trip).
// Phase 2: out[32x256] = AO * w_out^T + b_out, A-frags from LDS, B-frags from
// L2-resident Wout planes. K-order and hh/hl/lh term order identical to the
// previous separate gemm -> bit-identical accumulation.
__global__ __launch_bounds__(256) void fused_attn_kernel(
    const unsigned short* __restrict__ KG, const unsigned short* __restrict__ VTg,
    const unsigned short* __restrict__ Qb,
    const unsigned short* __restrict__ WOH, const unsigned short* __restrict__ WOL,
    const float* __restrict__ b_out, float* __restrict__ out)
{
    const int bb = blockIdx.y, q0 = blockIdx.x * 32;
    const int tid = threadIdx.x;
    const int lane = tid & 63, w = tid >> 6;
    const int c = lane & 15, g = lane >> 4;

    __shared__ __align__(16) unsigned short Pl[32 * PSTR];     // P[q][j] bf16
    __shared__ __align__(16) unsigned short VTl[32 * VSTR];    // V^T[d][j] bf16
    __shared__ __align__(16) unsigned short AOHl[32 * AOSTR];  // AO hi [tok][256]
    __shared__ __align__(16) unsigned short AOLl[32 * AOSTR];  // AO lo
    __shared__ float redl[4 * 32];
    __shared__ float invl[32];

    const unsigned short* KGb = KG + (size_t)bb * K_ * 256;
    const f32x4 zf = {0.0f, 0.0f, 0.0f, 0.0f};

    {   // P pad: j = 208..223 for all 32 q rows (exp writes cover only j<208)
        const int q = tid >> 3, cc = tid & 7;
        *(unsigned int*)&Pl[q * PSTR + 208 + cc * 2] = 0u;
    }

    for (int h = 0; h < H_; ++h) {
        // ---- stage V^T rows (pre-transposed, pre-padded in global): vector copy ----
        {
            const unsigned short* vsrc = VTg + ((size_t)bb * 256 + h * HD_) * 224;
            for (int i = tid; i < 32 * 28; i += 256) {
                const int d = i / 28, seg = i % 28;
                *(short8v*)&VTl[d * VSTR + seg * 8] = *(const short8v*)(vsrc + d * 224 + seg * 8);
            }
        }

        // ---- QK^T via MFMA: wave w handles j-tiles {w, w+4, w+8, (w+12)} ----
        short8v qa[2];
        #pragma unroll
        for (int qt = 0; qt < 2; ++qt)
            qa[qt] = *(const short8v*)(Qb + (size_t)(bb * S_ + q0 + qt*16 + c) * D_ + h * HD_ + g * 8);

        const int njt = (w == 0) ? 4 : 3;
        f32x4 acc[2][4];
        #pragma unroll
        for (int qt = 0; qt < 2; ++qt)
            #pragma unroll
            for (int t = 0; t < 4; ++t) acc[qt][t] = zf;

        for (int t = 0; t < njt; ++t) {
            const int jt = w + 4 * t;
            const int jc = min(jt * 16 + c, K_ - 1);
            const short8v kb = *(const short8v*)(KGb + (size_t)jc * 256 + h * HD_ + g * 8);
            acc[0][t] = __builtin_amdgcn_mfma_f32_16x16x32_bf16(qa[0], kb, acc[0][t], 0, 0, 0);
            acc[1][t] = __builtin_amdgcn_mfma_f32_16x16x32_bf16(qa[1], kb, acc[1][t], 0, 0, 0);
        }

        // exp (fp32), write P (bf16), accumulate row-sums
        float rs[2][4] = {{0,0,0,0},{0,0,0,0}};
        for (int t = 0; t < njt; ++t) {
            const int jg = (w + 4 * t) * 16 + c;
            const bool val = (jg < K_);
            #pragma unroll
            for (int qt = 0; qt < 2; ++qt) {
                #pragma unroll
                for (int r = 0; r < 4; ++r) {
                    const float e = val ? __expf(acc[qt][t][r] * SCALE_) : 0.0f;
                    rs[qt][r] += e;
                    Pl[(qt*16 + g*4 + r) * PSTR + jg] = f2bf(e);
                }
            }
        }
        #pragma unroll
        for (int qt = 0; qt < 2; ++qt)
            #pragma unroll
            for (int r = 0; r < 4; ++r) {
                float s = rs[qt][r];
                s += __shfl_xor(s, 1); s += __shfl_xor(s, 2);
                s += __shfl_xor(s, 4); s += __shfl_xor(s, 8);
                if (c == 0) redl[w * 32 + qt*16 + g*4 + r] = s;
            }

        __syncthreads();
        if (tid < 32)
            invl[tid] = 1.0f / (redl[tid] + redl[32 + tid] + redl[64 + tid] + redl[96 + tid]);
        __syncthreads();

        // ---- PV: O^T = V^T * P^T; wave w -> quadrant (dt = w>>1, qt2 = w&1) ----
        const int dt = w >> 1, qt2 = w & 1;
        f32x4 o = zf;
        const unsigned short* vb = &VTl[(dt*16 + c) * VSTR];
        const unsigned short* pb = &Pl[(qt2*16 + c) * PSTR];
        #pragma unroll
        for (int kt = 0; kt < 7; ++kt) {
            const short8v av = ld_bf8(vb + kt*32 + g*8);
            const short8v bv = ld_bf8(pb + kt*32 + g*8);
            o = __builtin_amdgcn_mfma_f32_16x16x32_bf16(av, bv, o, 0, 0, 0);
        }
        const float iv = invl[qt2*16 + c];
        // hi/lo split at the same rounding point as before; store to LDS AO
        const int aoff = (qt2*16 + c) * AOSTR + h * HD_ + dt*16 + g*4;
        ushort4 hh, ll;
        {
            const float v0 = o[0]*iv, v1 = o[1]*iv, v2 = o[2]*iv, v3 = o[3]*iv;
            hh.x = f2bf(v0); ll.x = f2bf(v0 - bf2f(hh.x));
            hh.y = f2bf(v1); ll.y = f2bf(v1 - bf2f(hh.y));
            hh.z = f2bf(v2); ll.z = f2bf(v2 - bf2f(hh.z));
            hh.w = f2bf(v3); ll.w = f2bf(v3 - bf2f(hh.w));
        }
        *(ushort4*)&AOHl[aoff] = hh;
        *(ushort4*)&AOLl[aoff] = ll;

        __syncthreads();   // AO/P/VT reads done before next head overwrites
    }

    // ---- phase 2: out[32 tok][256] = AO * Wout^T + b_out ----
    // wave w owns n-strip [w*64, w*64+64); A-frags from LDS AO planes.
    {
        const int nbase = w * 64;
        f32x4 acc2[2][4];
        #pragma unroll
        for (int mt = 0; mt < 2; ++mt)
            #pragma unroll
            for (int nt = 0; nt < 4; ++nt) acc2[mt][nt] = zf;

        #pragma unroll 2
        for (int ks = 0; ks < 8; ++ks) {
            short8v ah[2], al[2];
            #pragma unroll
            for (int mt = 0; mt < 2; ++mt) {
                const int ro = (mt*16 + c) * AOSTR + ks*32 + g*8;
                ah[mt] = *(const short8v*)&AOHl[ro];
                al[mt] = *(const short8v*)&AOLl[ro];
            }
            #pragma unroll
            for (int nt = 0; nt < 4; ++nt) {
                const size_t wr = (size_t)(nbase + nt*16 + c) * D_ + ks*32 + g*8;
                const short8v bh = *(const short8v*)(WOH + wr);
                const short8v bl = *(const short8v*)(WOL + wr);
                #pragma unroll
                for (int mt = 0; mt < 2; ++mt) {
                    acc2[mt][nt] = __builtin_amdgcn_mfma_f32_16x16x32_bf16(ah[mt], bh, acc2[mt][nt], 0, 0, 0);
                    acc2[mt][nt] = __builtin_amdgcn_mfma_f32_16x16x32_bf16(ah[mt], bl, acc2[mt][nt], 0, 0, 0);
                    acc2[mt][nt] = __builtin_amdgcn_mfma_f32_16x16x32_bf16(al[mt], bh, acc2[mt][nt], 0, 0, 0);
                }
            }
        }
        #pragma unroll
        for (int nt = 0; nt < 4; ++nt) {
            const int n = nbase + nt*16 + c;
            const float bv = b_out[n];
            #pragma unroll
            for (int mt = 0; mt < 2; ++mt) {
                const int m = mt*16 + g*4;
                #pragma unroll
                for (int r = 0; r < 4; ++r)
                    out[(size_t)(bb * S_ + q0 + m + r) * D_ + n] = acc2[mt][nt][r] + bv;
            }
        }
    }
}

extern "C" void kernel_launch(void* const* d_in, const int* in_sizes, int n_in,
                              void* d_out, int out_size, void* d_ws, size_t ws_size,
                              hipStream_t stream)
{
    const float* x     = (const float*)d_in[0];
    const float* w_in  = (const float*)d_in[1];
    const float* b_in  = (const float*)d_in[2];
    const float* w_out = (const float*)d_in[3];
    const float* b_out = (const float*)d_in[4];
    const float* gw1   = (const float*)d_in[5];
    const float* gb1   = (const float*)d_in[6];
    const float* gw2   = (const float*)d_in[7];
    // d_in[8] = gate_b2: constant inside monotone sigmoid -> doesn't affect top-k

    float* ws = (float*)d_ws;
    int* meta = (int*)(ws + OFF_META);
    int* kidx = (int*)(ws + OFF_KIDX);
    unsigned short* KG  = (unsigned short*)(ws + OFF_KG);
    unsigned short* VTg = (unsigned short*)(ws + OFF_VT);
    unsigned short* Qb  = (unsigned short*)(ws + OFF_Q);
    unsigned short* XH  = (unsigned short*)(ws + OFF_XH);
    unsigned short* XL  = (unsigned short*)(ws + OFF_XL);
    unsigned short* WIH = (unsigned short*)(ws + OFF_WIH);
    unsigned short* WIL = (unsigned short*)(ws + OFF_WIL);
    unsigned short* WOH = (unsigned short*)(ws + OFF_WOH);
    unsigned short* WOL = (unsigned short*)(ws + OFF_WOL);
    float* out = (float*)d_out;

    // gate + plane conversion (x, w_in, w_out) + meta zero
    gate_kernel<<<B_ * S_ / 8, 256, 0, stream>>>(x, gw1, gb1, gw2, w_in, w_out, ws);
    // exact-rank top-k with ticketed emit
    rank_kernel<<<B_ * 128, 256, 0, stream>>>(ws + OFF_IMP, kidx, meta);
    // fused Q projection + gathered K/V projection (V written pre-transposed)
    proj_kernel<<<dim3(160, 4), 256, 0, stream>>>(
        XH, XL, WIH, WIL, b_in, Qb, KG, VTg, kidx);
    // fused attention + out projection
    fused_attn_kernel<<<dim3(S_ / 32, B_), 256, 0, stream>>>(
        KG, VTg, Qb, WOH, WOL, b_out, out);
}

// Round 9
// 143.549 us; speedup vs baseline: 1.1972x; 1.1972x over previous
//
#include <hip/hip_runtime.h>
#include <hip/hip_bf16.h>

// Problem constants
#define B_  4
#define S_  2048
#define D_  256
#define H_  8
#define HD_ 32
#define K_  204          // int(2048 * 0.1)
#define SCALE_ 0.17677669529663687f  // 1/sqrt(32)

// ---- workspace layout (float offsets; all %4==0 -> 16B aligned) ----
#define OFF_IMP    0          // 8192 floats
#define OFF_META   8192       // 16 ints
#define OFF_KIDX   8208       // 1024 ints
#define OFF_KG     9232       // 208896 shorts [B][K_][256] bf16 (col = h*32+d)
#define OFF_VT     113680     // 229376 shorts [B][256][224] bf16 (V^T, cols 204.. zeroed)
#define OFF_Q      228368     // 2097152 shorts [B*S, D] bf16
#define OFF_XH     1276944    // 2097152 shorts: x hi plane
#define OFF_XL     2325520    // 2097152 shorts: x lo plane
#define OFF_AOH    3374096    // 2097152 shorts: attn-out hi plane
#define OFF_AOL    4422672    // 2097152 shorts: attn-out lo plane
#define OFF_WIH    5471248    // 196608 shorts: w_in (768x256) hi
#define OFF_WIL    5569552    // 196608 shorts: w_in lo
#define OFF_WOH    5667856    // 65536 shorts: w_out hi
#define OFF_WOL    5700624    // 65536 shorts: w_out lo
// total ~22.9 MB

#define GSTR 80    // gemm LDS row stride (shorts)
#define PSTR 228   // attn P row stride (shorts)
#define VSTR 232   // attn V^T LDS row stride (shorts; 464B = 16B-aligned rows)

typedef __attribute__((ext_vector_type(8))) short short8v;
typedef __attribute__((ext_vector_type(4))) float f32x4;

static __device__ __forceinline__ unsigned short f2bf(float f) {
    unsigned int u = __float_as_uint(f);
    u += 0x7FFFu + ((u >> 16) & 1u);      // round-to-nearest-even
    return (unsigned short)(u >> 16);
}
static __device__ __forceinline__ float bf2f(unsigned short h) {
    return __uint_as_float((unsigned int)h << 16);
}
static __device__ __forceinline__ short8v ld_bf8(const unsigned short* p) {
    union { unsigned int u[4]; short8v v; } cv;
    const uint2 a  = *(const uint2*)(p);
    const uint2 b2 = *(const uint2*)(p + 4);
    cv.u[0] = a.x; cv.u[1] = a.y; cv.u[2] = b2.x; cv.u[3] = b2.y;
    return cv.v;
}
// split 8 contiguous fp32 -> bf16 hi/lo planes (16B store each)
static __device__ __forceinline__ void split_store8(
    const float* __restrict__ src, unsigned short* dh, unsigned short* dl)
{
    short8v h, l;
    #pragma unroll
    for (int e = 0; e < 8; ++e) {
        const float f = src[e];
        const unsigned short hh = f2bf(f);
        h[e] = (short)hh;
        l[e] = (short)f2bf(f - bf2f(hh));
    }
    *(short8v*)dh = h;
    *(short8v*)dl = l;
}

// ---------------- kernel 1: gate MLP + x/weight plane conversion ----------------
__global__ __launch_bounds__(256) void gate_kernel(
    const float* __restrict__ x, const float* __restrict__ gw1,
    const float* __restrict__ gb1, const float* __restrict__ gw2,
    const float* __restrict__ w_in, const float* __restrict__ w_out, float* ws)
{
    const int t0 = blockIdx.x * 8;
    const int tid = threadIdx.x;
    __shared__ __align__(16) float xs[8 * D_];
    __shared__ float hred[8 * 64];

    const float4* src = (const float4*)(x + (size_t)t0 * D_);
    ((float4*)xs)[tid]       = src[tid];
    ((float4*)xs)[tid + 256] = src[tid + 256];
    __syncthreads();

    // emit x bf16 hi/lo planes from the staged tile (no extra global reads)
    {
        unsigned short* XH = (unsigned short*)(ws + OFF_XH);
        unsigned short* XL = (unsigned short*)(ws + OFF_XL);
        split_store8(xs + tid * 8, XH + (size_t)t0 * D_ + tid * 8,
                                   XL + (size_t)t0 * D_ + tid * 8);
    }
    // blocks 0..127: convert w_in (768x256) and w_out (256x256) to planes
    if (blockIdx.x < 128) {
        const int e0 = blockIdx.x * 2048 + tid * 8;
        if (e0 < 196608) {
            split_store8(w_in + e0, (unsigned short*)(ws + OFF_WIH) + e0,
                                    (unsigned short*)(ws + OFF_WIL) + e0);
        } else {
            const int e = e0 - 196608;
            split_store8(w_out + e, (unsigned short*)(ws + OFF_WOH) + e,
                                    (unsigned short*)(ws + OFF_WOL) + e);
        }
    }
    if (blockIdx.x == 0 && tid < 16) ((int*)(ws + OFF_META))[tid] = 0;

    const int c = tid & 3, f = tid >> 2;
    float4 wv[16];
    const float4* wr = (const float4*)(gw1 + (size_t)f * D_) + c;
    #pragma unroll
    for (int j = 0; j < 16; ++j) wv[j] = wr[j * 4];
    const float bb = gb1[f], g2 = gw2[f];

    #pragma unroll
    for (int tk = 0; tk < 8; ++tk) {
        const float4* xr = (const float4*)(xs + tk * D_) + c;
        float a = 0.0f;
        #pragma unroll
        for (int j = 0; j < 16; ++j) {
            float4 xv = xr[j * 4];
            a += wv[j].x*xv.x + wv[j].y*xv.y + wv[j].z*xv.z + wv[j].w*xv.w;
        }
        a += __shfl_xor(a, 1);
        a += __shfl_xor(a, 2);
        if (c == 0) hred[tk * 64 + f] = fmaxf(a + bb, 0.0f) * g2;
    }
    __syncthreads();

    const int tk = tid >> 5, ln = tid & 31;
    float s = hred[tk * 64 + ln] + hred[tk * 64 + ln + 32];
    #pragma unroll
    for (int o = 16; o; o >>= 1) s += __shfl_xor(s, o, 32);
    if (ln == 0) ws[OFF_IMP + t0 + tk] = s;
}

// ---------------- kernel 2: exact rank -> ticketed compact index (unsorted) ----------------
// kept set identical to lax.top_k (rank = #greater + #equal-with-smaller-index < K).
// Slot order nondeterministic; attention is key-order invariant (validated r4..r7).
__global__ __launch_bounds__(256) void rank_kernel(
    const float* __restrict__ ws_imp, int* kidx, int* meta)
{
    const int b  = blockIdx.x >> 7;
    const int ic = blockIdx.x & 127;
    const int tid = threadIdx.x;
    __shared__ __align__(16) float vs[S_];
    const float* src = ws_imp + b * S_;
    #pragma unroll
    for (int cc = 0; cc < 2; ++cc)
        ((float4*)vs)[tid + cc*256] = ((const float4*)src)[tid + cc*256];
    __syncthreads();

    const int il = tid >> 4;
    const int c  = tid & 15;
    const int i  = ic * 16 + il;
    const float vi = vs[i];
    int gt = 0, eq = 0;
    const float4* v4 = (const float4*)vs + c * 32;
    #pragma unroll 8
    for (int t = 0; t < 32; ++t) {
        const int j4 = (t + c) & 31;
        float4 w = v4[j4];
        const int base = c * 128 + j4 * 4;
        gt += (w.x > vi); eq += (w.x == vi) && (base + 0 < i);
        gt += (w.y > vi); eq += (w.y == vi) && (base + 1 < i);
        gt += (w.z > vi); eq += (w.z == vi) && (base + 2 < i);
        gt += (w.w > vi); eq += (w.w == vi) && (base + 3 < i);
    }
    int r = gt + eq;
    r += __shfl_xor(r, 1);
    r += __shfl_xor(r, 2);
    r += __shfl_xor(r, 4);
    r += __shfl_xor(r, 8);
    if (c == 0 && r < K_) {
        const int p = atomicAdd(&meta[2 + b], 1);
        kidx[b * K_ + p] = i;
    }
}

// ---------------- kernel 3: fused projection (Q GEMM + gathered KV GEMM) ----------------
// blockIdx.x < 128: Q tile  (m0 = x*64 of 8192 rows, n0 = y*64 of 256)
// else: KV tile for batch y (m = key slot of 256-pad, n = 512 cols; w_in rows 256..768)
// Split-bf16: C ~= Ah*Wh + Ah*Wl + Al*Wh, fp32 accum.
// K out: KG[b][j][256]; V out: transposed VT[b][d][224] with cols 204..223 zeroed.
__global__ __launch_bounds__(256) void proj_kernel(
    const unsigned short* __restrict__ XH, const unsigned short* __restrict__ XL,
    const unsigned short* __restrict__ WIH, const unsigned short* __restrict__ WIL,
    const float* __restrict__ b_in, unsigned short* __restrict__ Qb,
    unsigned short* __restrict__ KG, unsigned short* __restrict__ VTg,
    const int* __restrict__ kidx)
{
    __shared__ __align__(16) unsigned short Ash[64 * GSTR];
    __shared__ __align__(16) unsigned short Asl[64 * GSTR];
    __shared__ __align__(16) unsigned short Bsh[64 * GSTR];
    __shared__ __align__(16) unsigned short Bsl[64 * GSTR];

    const int tid = threadIdx.x;
    const bool isQ = (blockIdx.x < 128);
    const int lane = tid & 63, w = tid >> 6;
    const int c = lane & 15, g = lane >> 4;
    const int mq = w >> 1, nq = w & 1;
    const int srow = tid >> 2, sseg = tid & 3;

    int m0, n0, b = blockIdx.y;
    size_t arow;   // A-plane row index
    int brow;      // w_in row index
    if (isQ) {
        m0 = blockIdx.x * 64; n0 = blockIdx.y * 64;
        arow = (size_t)(m0 + srow);
        brow = n0 + srow;
    } else {
        const int kx = blockIdx.x - 128;
        m0 = (kx & 3) * 64; n0 = (kx >> 2) * 64;
        const int tok = kidx[b * K_ + min(m0 + srow, K_ - 1)];
        arow = (size_t)b * S_ + tok;
        brow = D_ + n0 + srow;
    }
    const unsigned short* Aph = XH + arow * D_ + sseg * 16;
    const unsigned short* Apl = XL + arow * D_ + sseg * 16;
    const unsigned short* Bph = WIH + (size_t)brow * D_ + sseg * 16;
    const unsigned short* Bpl = WIL + (size_t)brow * D_ + sseg * 16;

    const f32x4 zf = {0.0f, 0.0f, 0.0f, 0.0f};
    f32x4 acc[2][2] = {{zf, zf}, {zf, zf}};

    short8v arh[2], arl[2], brh[2], brl[2];
    #pragma unroll
    for (int u = 0; u < 2; ++u) {
        arh[u] = *(const short8v*)(Aph + u*8); arl[u] = *(const short8v*)(Apl + u*8);
        brh[u] = *(const short8v*)(Bph + u*8); brl[u] = *(const short8v*)(Bpl + u*8);
    }

    for (int k0 = 0; k0 < D_; k0 += 64) {
        __syncthreads();
        #pragma unroll
        for (int u = 0; u < 2; ++u) {
            *(short8v*)&Ash[srow*GSTR + sseg*16 + u*8] = arh[u];
            *(short8v*)&Asl[srow*GSTR + sseg*16 + u*8] = arl[u];
            *(short8v*)&Bsh[srow*GSTR + sseg*16 + u*8] = brh[u];
            *(short8v*)&Bsl[srow*GSTR + sseg*16 + u*8] = brl[u];
        }
        __syncthreads();
        if (k0 + 64 < D_) {
            #pragma unroll
            for (int u = 0; u < 2; ++u) {
                arh[u] = *(const short8v*)(Aph + k0 + 64 + u*8);
                arl[u] = *(const short8v*)(Apl + k0 + 64 + u*8);
                brh[u] = *(const short8v*)(Bph + k0 + 64 + u*8);
                brl[u] = *(const short8v*)(Bpl + k0 + 64 + u*8);
            }
        }
        #pragma unroll
        for (int ks = 0; ks < 2; ++ks) {
            short8v am[2][2], bm[2][2];
            #pragma unroll
            for (int t = 0; t < 2; ++t) {
                const int ra = (mq*32 + t*16 + c) * GSTR + ks*32 + g*8;
                am[t][0] = *(const short8v*)&Ash[ra];
                am[t][1] = *(const short8v*)&Asl[ra];
                const int rb = (nq*32 + t*16 + c) * GSTR + ks*32 + g*8;
                bm[t][0] = *(const short8v*)&Bsh[rb];
                bm[t][1] = *(const short8v*)&Bsl[rb];
            }
            #pragma unroll
            for (int mt = 0; mt < 2; ++mt)
                #pragma unroll
                for (int nt = 0; nt < 2; ++nt) {
                    acc[mt][nt] = __builtin_amdgcn_mfma_f32_16x16x32_bf16(am[mt][0], bm[nt][0], acc[mt][nt], 0, 0, 0);
                    acc[mt][nt] = __builtin_amdgcn_mfma_f32_16x16x32_bf16(am[mt][0], bm[nt][1], acc[mt][nt], 0, 0, 0);
                    acc[mt][nt] = __builtin_amdgcn_mfma_f32_16x16x32_bf16(am[mt][1], bm[nt][0], acc[mt][nt], 0, 0, 0);
                }
        }
    }

    if (isQ) {
        #pragma unroll
        for (int nt = 0; nt < 2; ++nt) {
            const int n = n0 + nq*32 + nt*16 + c;
            const float bv = b_in[n];
            #pragma unroll
            for (int mt = 0; mt < 2; ++mt) {
                const int m = m0 + mq*32 + mt*16 + g*4;
                #pragma unroll
                for (int r = 0; r < 4; ++r)
                    Qb[(size_t)(m + r) * D_ + n] = f2bf(acc[mt][nt][r] + bv);
            }
        }
    } else {
        #pragma unroll
        for (int nt = 0; nt < 2; ++nt) {
            const int n = n0 + nq*32 + nt*16 + c;           // 0..511
            const float bv = b_in[D_ + n];
            #pragma unroll
            for (int mt = 0; mt < 2; ++mt) {
                const int j = m0 + mq*32 + mt*16 + g*4;     // key slot
                #pragma unroll
                for (int r = 0; r < 4; ++r) {
                    const int jj = j + r;
                    if (n < 256) {
                        if (jj < K_)
                            KG[((size_t)b * K_ + jj) * 256 + n] = f2bf(acc[mt][nt][r] + bv);
                    } else {
                        if (jj < 224)
                            VTg[((size_t)b * 256 + (n - 256)) * 224 + jj] =
                                (jj < K_) ? f2bf(acc[mt][nt][r] + bv) : (unsigned short)0;
                    }
                }
            }
        }
    }
}

// ---------------- kernel 4: MFMA split-bf16 GEMM (out projection, fp32 out) ----------------
__global__ __launch_bounds__(256) void gemm_kernel(
    const unsigned short* __restrict__ Ah, const unsigned short* __restrict__ Al,
    const unsigned short* __restrict__ Bh, const unsigned short* __restrict__ Bl,
    const float* __restrict__ bias, float* __restrict__ Cf)
{
    __shared__ __align__(16) unsigned short Ash[64 * GSTR];
    __shared__ __align__(16) unsigned short Asl[64 * GSTR];
    __shared__ __align__(16) unsigned short Bsh[64 * GSTR];
    __shared__ __align__(16) unsigned short Bsl[64 * GSTR];

    const int tid = threadIdx.x;
    const int m0 = blockIdx.x * 64, n0 = blockIdx.y * 64;
    const int lane = tid & 63, w = tid >> 6;
    const int c = lane & 15, g = lane >> 4;
    const int mq = w >> 1, nq = w & 1;

    const f32x4 zf = {0.0f, 0.0f, 0.0f, 0.0f};
    f32x4 acc[2][2] = {{zf, zf}, {zf, zf}};

    const int srow = tid >> 2, sseg = tid & 3;
    const unsigned short* Aph = Ah + (size_t)(m0 + srow) * D_ + sseg * 16;
    const unsigned short* Apl = Al + (size_t)(m0 + srow) * D_ + sseg * 16;
    const unsigned short* Bph = Bh + (size_t)(n0 + srow) * D_ + sseg * 16;
    const unsigned short* Bpl = Bl + (size_t)(n0 + srow) * D_ + sseg * 16;

    short8v arh[2], arl[2], brh[2], brl[2];
    #pragma unroll
    for (int u = 0; u < 2; ++u) {
        arh[u] = *(const short8v*)(Aph + u*8); arl[u] = *(const short8v*)(Apl + u*8);
        brh[u] = *(const short8v*)(Bph + u*8); brl[u] = *(const short8v*)(Bpl + u*8);
    }

    for (int k0 = 0; k0 < D_; k0 += 64) {
        __syncthreads();
        #pragma unroll
        for (int u = 0; u < 2; ++u) {
            *(short8v*)&Ash[srow*GSTR + sseg*16 + u*8] = arh[u];
            *(short8v*)&Asl[srow*GSTR + sseg*16 + u*8] = arl[u];
            *(short8v*)&Bsh[srow*GSTR + sseg*16 + u*8] = brh[u];
            *(short8v*)&Bsl[srow*GSTR + sseg*16 + u*8] = brl[u];
        }
        __syncthreads();
        if (k0 + 64 < D_) {
            #pragma unroll
            for (int u = 0; u < 2; ++u) {
                arh[u] = *(const short8v*)(Aph + k0 + 64 + u*8);
                arl[u] = *(const short8v*)(Apl + k0 + 64 + u*8);
                brh[u] = *(const short8v*)(Bph + k0 + 64 + u*8);
                brl[u] = *(const short8v*)(Bpl + k0 + 64 + u*8);
            }
        }
        #pragma unroll
        for (int ks = 0; ks < 2; ++ks) {
            short8v am[2][2], bm[2][2];
            #pragma unroll
            for (int t = 0; t < 2; ++t) {
                const int ra = (mq*32 + t*16 + c) * GSTR + ks*32 + g*8;
                am[t][0] = *(const short8v*)&Ash[ra];
                am[t][1] = *(const short8v*)&Asl[ra];
                const int rb = (nq*32 + t*16 + c) * GSTR + ks*32 + g*8;
                bm[t][0] = *(const short8v*)&Bsh[rb];
                bm[t][1] = *(const short8v*)&Bsl[rb];
            }
            #pragma unroll
            for (int mt = 0; mt < 2; ++mt)
                #pragma unroll
                for (int nt = 0; nt < 2; ++nt) {
                    acc[mt][nt] = __builtin_amdgcn_mfma_f32_16x16x32_bf16(am[mt][0], bm[nt][0], acc[mt][nt], 0, 0, 0);
                    acc[mt][nt] = __builtin_amdgcn_mfma_f32_16x16x32_bf16(am[mt][0], bm[nt][1], acc[mt][nt], 0, 0, 0);
                    acc[mt][nt] = __builtin_amdgcn_mfma_f32_16x16x32_bf16(am[mt][1], bm[nt][0], acc[mt][nt], 0, 0, 0);
                }
        }
    }
    #pragma unroll
    for (int nt = 0; nt < 2; ++nt) {
        const int n = n0 + nq*32 + nt*16 + c;
        const float bv = bias[n];
        #pragma unroll
        for (int mt = 0; mt < 2; ++mt) {
            const int m = m0 + mq*32 + mt*16 + g*4;
            #pragma unroll
            for (int r = 0; r < 4; ++r)
                Cf[(size_t)(m + r) * D_ + n] = acc[mt][nt][r] + bv;
        }
    }
}

// ---------------- kernel 5: attention core (bf16 in, planes out) ----------------
__global__ __launch_bounds__(256) void attn_kernel(
    const unsigned short* __restrict__ KG, const unsigned short* __restrict__ VTg,
    const unsigned short* __restrict__ Qb,
    unsigned short* __restrict__ aoh, unsigned short* __restrict__ aol)
{
    const int b = blockIdx.z, h = blockIdx.y, q0 = blockIdx.x * 32;
    const int tid = threadIdx.x;
    const int lane = tid & 63, w = tid >> 6;
    const int c = lane & 15, g = lane >> 4;

    __shared__ __align__(16) unsigned short Pl[32 * PSTR];    // P[q][j] bf16
    __shared__ __align__(16) unsigned short VTl[32 * VSTR];   // V^T[d][j] bf16
    __shared__ float redl[4 * 32];
    __shared__ float invl[32];

    const unsigned short* KGb = KG + (size_t)b * K_ * 256;

    // ---- stage V^T rows (pre-transposed, pre-padded in global): vector copy ----
    {
        const unsigned short* vsrc = VTg + ((size_t)b * 256 + h * HD_) * 224;
        for (int i = tid; i < 32 * 28; i += 256) {
            const int d = i / 28, seg = i % 28;
            *(short8v*)&VTl[d * VSTR + seg * 8] = *(const short8v*)(vsrc + d * 224 + seg * 8);
        }
    }
    {   // P pad: j = 208..223 for all 32 q rows
        const int q = tid >> 3, cc = tid & 7;
        *(unsigned int*)&Pl[q * PSTR + 208 + cc * 2] = 0u;
    }

    // ---- QK^T via MFMA: wave w handles j-tiles {w, w+4, w+8, (w+12)} ----
    short8v qa[2];
    #pragma unroll
    for (int qt = 0; qt < 2; ++qt)
        qa[qt] = *(const short8v*)(Qb + (size_t)(b * S_ + q0 + qt*16 + c) * D_ + h * HD_ + g * 8);

    const int njt = (w == 0) ? 4 : 3;
    f32x4 acc[2][4];
    const f32x4 zf = {0.0f, 0.0f, 0.0f, 0.0f};
    #pragma unroll
    for (int qt = 0; qt < 2; ++qt)
        #pragma unroll
        for (int t = 0; t < 4; ++t) acc[qt][t] = zf;

    for (int t = 0; t < njt; ++t) {
        const int jt = w + 4 * t;
        const int jc = min(jt * 16 + c, K_ - 1);
        const short8v kb = *(const short8v*)(KGb + (size_t)jc * 256 + h * HD_ + g * 8);
        acc[0][t] = __builtin_amdgcn_mfma_f32_16x16x32_bf16(qa[0], kb, acc[0][t], 0, 0, 0);
        acc[1][t] = __builtin_amdgcn_mfma_f32_16x16x32_bf16(qa[1], kb, acc[1][t], 0, 0, 0);
    }

    // exp (fp32), write P (bf16), accumulate row-sums
    float rs[2][4] = {{0,0,0,0},{0,0,0,0}};
    for (int t = 0; t < njt; ++t) {
        const int jg = (w + 4 * t) * 16 + c;
        const bool val = (jg < K_);
        #pragma unroll
        for (int qt = 0; qt < 2; ++qt) {
            #pragma unroll
            for (int r = 0; r < 4; ++r) {
                const float e = val ? __expf(acc[qt][t][r] * SCALE_) : 0.0f;
                rs[qt][r] += e;
                Pl[(qt*16 + g*4 + r) * PSTR + jg] = f2bf(e);
            }
        }
    }
    #pragma unroll
    for (int qt = 0; qt < 2; ++qt)
        #pragma unroll
        for (int r = 0; r < 4; ++r) {
            float s = rs[qt][r];
            s += __shfl_xor(s, 1); s += __shfl_xor(s, 2);
            s += __shfl_xor(s, 4); s += __shfl_xor(s, 8);
            if (c == 0) redl[w * 32 + qt*16 + g*4 + r] = s;
        }

    __syncthreads();
    if (tid < 32)
        invl[tid] = 1.0f / (redl[tid] + redl[32 + tid] + redl[64 + tid] + redl[96 + tid]);
    __syncthreads();

    // ---- PV: O^T = V^T * P^T; wave w -> quadrant (dt = w>>1, qt2 = w&1) ----
    const int dt = w >> 1, qt2 = w & 1;
    f32x4 o = zf;
    const unsigned short* vb = &VTl[(dt*16 + c) * VSTR];
    const unsigned short* pb = &Pl[(qt2*16 + c) * PSTR];
    #pragma unroll
    for (int kt = 0; kt < 7; ++kt) {
        const short8v av = ld_bf8(vb + kt*32 + g*8);
        const short8v bv = ld_bf8(pb + kt*32 + g*8);
        o = __builtin_amdgcn_mfma_f32_16x16x32_bf16(av, bv, o, 0, 0, 0);
    }
    const float iv = invl[qt2*16 + c];
    const size_t oidx = (size_t)(b * S_ + q0 + qt2*16 + c) * D_ + h * HD_ + dt*16 + g*4;
    ushort4 hh, ll;
    {
        const float v0 = o[0]*iv, v1 = o[1]*iv, v2 = o[2]*iv, v3 = o[3]*iv;
        hh.x = f2bf(v0); ll.x = f2bf(v0 - bf2f(hh.x));
        hh.y = f2bf(v1); ll.y = f2bf(v1 - bf2f(hh.y));
        hh.z = f2bf(v2); ll.z = f2bf(v2 - bf2f(hh.z));
        hh.w = f2bf(v3); ll.w = f2bf(v3 - bf2f(hh.w));
    }
    *(ushort4*)(aoh + oidx) = hh;
    *(ushort4*)(aol + oidx) = ll;
}

extern "C" void kernel_launch(void* const* d_in, const int* in_sizes, int n_in,
                              void* d_out, int out_size, void* d_ws, size_t ws_size,
                              hipStream_t stream)
{
    const float* x     = (const float*)d_in[0];
    const float* w_in  = (const float*)d_in[1];
    const float* b_in  = (const float*)d_in[2];
    const float* w_out = (const float*)d_in[3];
    const float* b_out = (const float*)d_in[4];
    const float* gw1   = (const float*)d_in[5];
    const float* gb1   = (const float*)d_in[6];
    const float* gw2   = (const float*)d_in[7];
    // d_in[8] = gate_b2: constant inside monotone sigmoid -> doesn't affect top-k

    float* ws = (float*)d_ws;
    int* meta = (int*)(ws + OFF_META);
    int* kidx = (int*)(ws + OFF_KIDX);
    unsigned short* KG  = (unsigned short*)(ws + OFF_KG);
    unsigned short* VTg = (unsigned short*)(ws + OFF_VT);
    unsigned short* Qb  = (unsigned short*)(ws + OFF_Q);
    unsigned short* XH  = (unsigned short*)(ws + OFF_XH);
    unsigned short* XL  = (unsigned short*)(ws + OFF_XL);
    unsigned short* AOH = (unsigned short*)(ws + OFF_AOH);
    unsigned short* AOL = (unsigned short*)(ws + OFF_AOL);
    unsigned short* WIH = (unsigned short*)(ws + OFF_WIH);
    unsigned short* WIL = (unsigned short*)(ws + OFF_WIL);
    unsigned short* WOH = (unsigned short*)(ws + OFF_WOH);
    unsigned short* WOL = (unsigned short*)(ws + OFF_WOL);
    float* out = (float*)d_out;

    // gate + plane conversion (x, w_in, w_out) + meta zero
    gate_kernel<<<B_ * S_ / 8, 256, 0, stream>>>(x, gw1, gb1, gw2, w_in, w_out, ws);
    // exact-rank top-k with ticketed emit
    rank_kernel<<<B_ * 128, 256, 0, stream>>>(ws + OFF_IMP, kidx, meta);
    // fused Q projection + gathered K/V projection (V written pre-transposed)
    proj_kernel<<<dim3(160, 4), 256, 0, stream>>>(
        XH, XL, WIH, WIL, b_in, Qb, KG, VTg, kidx);
    // attention
    attn_kernel<<<dim3(S_ / 32, H_, B_), 256, 0, stream>>>(KG, VTg, Qb, AOH, AOL);
    // out = AO @ w_out^T + b_out  (fp32 output)
    gemm_kernel<<<dim3(B_ * S_ / 64, D_ / 64), 256, 0, stream>>>(
        AOH, AOL, WOH, WOL, b_out, out);
}